// Round 14
// baseline (39.091 us; speedup 1.0000x reference)
//
#include <hip/hip_runtime.h>
#include <hip/hip_bf16.h>

typedef __attribute__((ext_vector_type(8))) short short8;
typedef __attribute__((ext_vector_type(16))) float floatx16;

#define B_ROWS 8192
#define DIM 128
#define NPAIR 4095
// rows scaled by sqrt(log2(e)) so S_mfma = S * log2(e) and exp(S) = exp2(S_mfma)
#define RSCALE 1.2011224087864498f

#define GLOAD_LDS16(gp, lp)                                                     \
    __builtin_amdgcn_global_load_lds(                                           \
        (const __attribute__((address_space(1))) void*)(gp),                    \
        (__attribute__((address_space(3))) void*)(lp), 16, 0, 0)

// ---------------- zero Z (fallback path only) ----------------
__global__ void kzero(float* __restrict__ Z) {
    int i = blockIdx.x * 256 + threadIdx.x;
    if (i < B_ROWS) Z[i] = 0.f;
}

// ------------- prep: normalize rows -> bf16 (scaled), exact fp32 pair dots -------------
// 1024 blocks x 256 thr; wave W: rows 2W (lanes 0-31), 2W+1 (lanes 32-63), float4/lane.
__global__ void kprep(const float* __restrict__ X, __hip_bfloat16* __restrict__ XN,
                      float* __restrict__ pairT, float* __restrict__ out) {
    const int wid = threadIdx.x >> 6;
    const int lane = threadIdx.x & 63;
    const int j = lane & 31;
    const int W = blockIdx.x * 4 + wid;  // wave index == pair index
    const int row = 2 * W + (lane >> 5);

    const float4 v = *reinterpret_cast<const float4*>(X + row * DIM + j * 4);
    float ss = v.x * v.x + v.y * v.y + v.z * v.z + v.w * v.w;
    #pragma unroll
    for (int m = 1; m < 32; m <<= 1) ss += __shfl_xor(ss, m, 64);  // within half
    const float rn = ss > 0.f ? rsqrtf(ss) : 0.f;

    // exact pair similarity via cross-half shuffle
    float4 pv;
    pv.x = __shfl_xor(v.x, 32, 64);
    pv.y = __shfl_xor(v.y, 32, 64);
    pv.z = __shfl_xor(v.z, 32, 64);
    pv.w = __shfl_xor(v.w, 32, 64);
    float pd = v.x * pv.x + v.y * pv.y + v.z * pv.z + v.w * pv.w;
    #pragma unroll
    for (int m = 1; m < 32; m <<= 1) pd += __shfl_xor(pd, m, 64);
    const float rno = __shfl_xor(rn, 32, 64);
    if (lane == 0 && W < NPAIR) pairT[W] = pd * rn * rno;

    // bf16 write (scaled)
    const float sc = rn * RSCALE;
    __hip_bfloat162 h0 = __float22bfloat162_rn(make_float2(v.x * sc, v.y * sc));
    __hip_bfloat162 h1 = __float22bfloat162_rn(make_float2(v.z * sc, v.w * sc));
    struct B4 { __hip_bfloat162 a, b; };
    *reinterpret_cast<B4*>(XN + row * DIM + j * 4) = B4{h0, h1};

    if (W == 0 && lane == 0) out[0] = 0.f;
}

// ---- stage one 64x128 bf16 half-slab to LDS (linear dest, pre-swizzled source) ----
// LDS[row][colL] = global[row][colL ^ ((row&15)<<3)] (16B-chunk XOR over 4 row bits)
__device__ __forceinline__ void stage_half(const __hip_bfloat16* __restrict__ gsrc,
                                           __hip_bfloat16* lbuf, int tid) {
    const int wid = tid >> 6;
    const int lane = tid & 63;
    #pragma unroll
    for (int it = 0; it < 4; ++it) {
        const int woff = it * 2048 + wid * 512;  // wave-uniform elem offset
        const int e = woff + lane * 8;
        const int src = (e & ~127) | ((e & 127) ^ (((e >> 7) & 15) << 3));
        GLOAD_LDS16(gsrc + src, lbuf + woff);
    }
}

// ------------- main: row-panel GEMM, 32x32x16 MFMA, 3-buffer counted-vmcnt -------------
// grid (8, 64): y = row panel rb (128 rows), x = col group g (8 tiles = 16 slabs).
// 4 waves 2x2 (wr row-half, wc col-half): wave owns 64 rows x 32 cols per slab-phase.
// Per phase: 16x mfma_f32_32x32x16_bf16 (2 row-tiles x 8 k-steps), exp2 + row-acc.
template <bool USEP>
__global__ void __launch_bounds__(256, 2) kgemm(const __hip_bfloat16* __restrict__ XN,
                                                float* __restrict__ ZP) {
    __shared__ __hip_bfloat16 Bs[3][64 * DIM];

    const int tid = threadIdx.x;
    const int wid = tid >> 6;
    const int lane = tid & 63;
    const int c31 = lane & 31;
    const int h = lane >> 5;
    const int wr = wid >> 1;
    const int wc = wid & 1;
    const int rb = blockIdx.y;
    const int g = blockIdx.x;

    // ---- A: 64 rows in regs: a[t][ks], row = rb*128 + wr*64 + t*32 + c31,
    //      elems [ks*16 + h*8, +8) ----
    short8 a[2][8];
    #pragma unroll
    for (int t = 0; t < 2; ++t) {
        const __hip_bfloat16* Ab = XN + (size_t)(rb * 128 + wr * 64 + t * 32 + c31) * DIM + h * 8;
        #pragma unroll
        for (int ks = 0; ks < 8; ++ks)
            a[t][ks] = *reinterpret_cast<const short8*>(Ab + ks * 16);
    }

    float rp[2][16];
    #pragma unroll
    for (int t = 0; t < 2; ++t)
        #pragma unroll
        for (int q = 0; q < 16; ++q) rp[t][q] = 0.f;

    const floatx16 z16 = {0.f, 0.f, 0.f, 0.f, 0.f, 0.f, 0.f, 0.f,
                          0.f, 0.f, 0.f, 0.f, 0.f, 0.f, 0.f, 0.f};

    // prologue: stage slabs 0,1 (slab s = tile g*8 + (s>>1), half s&1)
    stage_half(XN + (size_t)(g * 8) * 128 * DIM, Bs[0], tid);
    stage_half(XN + ((size_t)(g * 8) * 128 + 64) * DIM, Bs[1], tid);

    const int brow = wc * 32 + c31;                       // staged-local col row
    const int bco = ((brow & 15) << 3);                   // read-side swizzle
    const int myrow_base = wr * 64;                       // wave row offset in tile

    for (int t = 0; t < 16; ++t) {
        if (t < 15)
            asm volatile("s_waitcnt vmcnt(4)" ::: "memory");
        else
            asm volatile("s_waitcnt vmcnt(0)" ::: "memory");
        __builtin_amdgcn_s_barrier();  // raw barrier: no drain

        if (t + 2 < 16)
            stage_half(XN + ((size_t)(g * 8 + ((t + 2) >> 1)) * 128 + ((t + 2) & 1) * 64) * DIM,
                       Bs[(t + 2) % 3], tid);

        const __hip_bfloat16* Bt = Bs[t % 3];
        const bool dzero = (g * 8 + (t >> 1) == rb) && ((t & 1) == wr);

        __builtin_amdgcn_s_setprio(1);
        // B frags: B[k][col] with col = brow; 8 k-steps x 16B, swizzled read
        short8 b[8];
        #pragma unroll
        for (int ks = 0; ks < 8; ++ks)
            b[ks] = *reinterpret_cast<const short8*>(
                &Bt[brow * DIM + ((ks * 16 + h * 8) ^ bco)]);

        floatx16 acc[2];
        #pragma unroll
        for (int tt = 0; tt < 2; ++tt)
            acc[tt] = __builtin_amdgcn_mfma_f32_32x32x16_bf16(a[tt][0], b[0], z16, 0, 0, 0);
        #pragma unroll
        for (int ks = 1; ks < 8; ++ks)
            #pragma unroll
            for (int tt = 0; tt < 2; ++tt)
                acc[tt] = __builtin_amdgcn_mfma_f32_32x32x16_bf16(a[tt][ks], b[ks], acc[tt], 0, 0, 0);
        __builtin_amdgcn_s_setprio(0);

        // epilogue: exp2, diagonal exclusion on aligned slab, row accumulate
        if (dzero) {
            #pragma unroll
            for (int tt = 0; tt < 2; ++tt)
                #pragma unroll
                for (int q = 0; q < 16; ++q) {
                    const int rl = myrow_base + tt * 32 + (q & 3) + 8 * (q >> 2) + 4 * h;
                    const int cl = myrow_base + wc * 32 + c31;  // same 64-block: wr==(t&1)
                    float e = __builtin_amdgcn_exp2f(acc[tt][q]);
                    // local row within the 64-row block vs local col within slab
                    if (tt * 32 + (q & 3) + 8 * (q >> 2) + 4 * h == wc * 32 + c31) e = 0.f;
                    rp[tt][q] += e;
                    (void)rl; (void)cl;
                }
        } else {
            #pragma unroll
            for (int tt = 0; tt < 2; ++tt)
                #pragma unroll
                for (int q = 0; q < 16; ++q)
                    rp[tt][q] += __builtin_amdgcn_exp2f(acc[tt][q]);
        }
    }

    // ---- row sums: reduce over the 32 lanes of each half (cols), store P[row][slot] ----
    #pragma unroll
    for (int tt = 0; tt < 2; ++tt)
        #pragma unroll
        for (int q = 0; q < 16; ++q) {
            float v = rp[tt][q];
            v += __shfl_xor(v, 1, 64);
            v += __shfl_xor(v, 2, 64);
            v += __shfl_xor(v, 4, 64);
            v += __shfl_xor(v, 8, 64);
            v += __shfl_xor(v, 16, 64);
            if (c31 == 0) {
                const int row = rb * 128 + wr * 64 + tt * 32 + (q & 3) + 8 * (q >> 2) + 4 * h;
                if (USEP)
                    ZP[row * 16 + (g * 2 + wc)] = v;
                else
                    atomicAdd(&ZP[row], v);
            }
        }
}

// ------------- final (P path): Z[r] = sum_16 P[r][slot] (contiguous); loss reduce -------------
__global__ void kfinalP(const float* __restrict__ P, const float* __restrict__ pairT,
                        float* __restrict__ out) {
    const int r = blockIdx.x * 256 + threadIdx.x;
    float s = 0.f;
    if (r < B_ROWS - 2) {
        const float4* p4 = reinterpret_cast<const float4*>(P + r * 16);
        float z = 0.f;
        #pragma unroll
        for (int i = 0; i < 4; ++i) {
            const float4 v = p4[i];
            z += v.x + v.y + v.z + v.w;
        }
        s = logf(z);
    }
    if (r < NPAIR) s -= 2.f * pairT[r];
    #pragma unroll
    for (int m = 1; m < 64; m <<= 1) s += __shfl_xor(s, m, 64);
    __shared__ float red[4];
    const int wid = threadIdx.x >> 6;
    const int lane = threadIdx.x & 63;
    if (lane == 0) red[wid] = s;
    __syncthreads();
    if (threadIdx.x == 0) {
        float tsum = red[0] + red[1] + red[2] + red[3];
        atomicAdd(out, tsum / (float)B_ROWS);
    }
}

// ------------- final (Z fallback path) -------------
__global__ void kfinalZ(const float* __restrict__ Z, const float* __restrict__ pairT,
                        float* __restrict__ out) {
    float s = 0.f;
    for (int r = threadIdx.x; r < B_ROWS - 2; r += 1024) s += logf(Z[r]);
    for (int p = threadIdx.x; p < NPAIR; p += 1024) s -= 2.f * pairT[p];
    #pragma unroll
    for (int m = 1; m < 64; m <<= 1) s += __shfl_xor(s, m, 64);
    __shared__ float red[16];
    const int wid = threadIdx.x >> 6;
    const int lane = threadIdx.x & 63;
    if (lane == 0) red[wid] = s;
    __syncthreads();
    if (threadIdx.x == 0) {
        float t = 0.f;
        #pragma unroll
        for (int i = 0; i < 16; ++i) t += red[i];
        out[0] = t / (float)B_ROWS;
    }
}

extern "C" void kernel_launch(void* const* d_in, const int* in_sizes, int n_in,
                              void* d_out, int out_size, void* d_ws, size_t ws_size,
                              hipStream_t stream) {
    (void)in_sizes; (void)n_in; (void)out_size;
    const float* X = (const float*)d_in[0];
    float* out = (float*)d_out;
    char* ws = (char*)d_ws;

    float* Z = (float*)ws;                                   // 32 KB (fallback)
    float* pairT = (float*)(ws + 32768);                     // 16 KB
    __hip_bfloat16* XN = (__hip_bfloat16*)(ws + 49152);      // 2 MB
    float* P = (float*)(ws + 49152 + 2097152);               // 512 KB (8192 x 16 f32)
    const size_t need = 49152 + 2097152 + (size_t)16 * B_ROWS * 4;
    const bool useP = ws_size >= need;

    kprep<<<1024, 256, 0, stream>>>(X, XN, pairT, out);
    if (useP) {
        kgemm<true><<<dim3(8, 64), 256, 0, stream>>>(XN, P);
        kfinalP<<<32, 256, 0, stream>>>(P, pairT, out);
    } else {
        kzero<<<32, 256, 0, stream>>>(Z);
        kgemm<false><<<dim3(8, 64), 256, 0, stream>>>(XN, Z);
        kfinalZ<<<1, 1024, 0, stream>>>(Z, pairT, out);
    }
}